// Round 11
// baseline (420.099 us; speedup 1.0000x reference)
//
#include <hip/hip_runtime.h>

typedef __attribute__((ext_vector_type(8))) short     bf16x8;
typedef __attribute__((ext_vector_type(4))) float     f32x4;
typedef __attribute__((ext_vector_type(2))) float     f32x2;
typedef __attribute__((ext_vector_type(4))) unsigned short u16x4;

#define OUT_STRIDE 1086
#define NS_STRIDE 1026
#define NS_BASE (4096*1086)

__device__ __forceinline__ unsigned short f2bf(float x) {
  unsigned int u = __float_as_uint(x);
  unsigned int r = (u + 0x7FFFu + ((u >> 16) & 1u)) >> 16;
  return (unsigned short)r;
}
__device__ __forceinline__ float bf2f(unsigned short u) {
  union { unsigned int i; float f; } v; v.i = ((unsigned int)u) << 16; return v.f;
}
__device__ __forceinline__ float sigmoidf(float x) { return 1.f / (1.f + expf(-x)); }

__device__ __forceinline__ void gld_lds16(const void* g, void* l) {
  __builtin_amdgcn_global_load_lds((const __attribute__((address_space(1))) void*)g,
                                   (__attribute__((address_space(3))) void*)l, 16, 0, 0);
}
#define MFMA(a, b, c) __builtin_amdgcn_mfma_f32_16x16x32_bf16(a, b, c, 0, 0, 0)

// vmcnt wait with compile-time-folded immediate (t is constant after unroll)
#define VMW(n) { if ((n) == 36) asm volatile("s_waitcnt vmcnt(36)" ::: "memory");    \
                 else if ((n) == 24) asm volatile("s_waitcnt vmcnt(24)" ::: "memory");\
                 else if ((n) == 16) asm volatile("s_waitcnt vmcnt(16)" ::: "memory");\
                 else if ((n) == 12) asm volatile("s_waitcnt vmcnt(12)" ::: "memory");\
                 else if ((n) == 8)  asm volatile("s_waitcnt vmcnt(8)"  ::: "memory");\
                 else asm volatile("s_waitcnt vmcnt(0)" ::: "memory"); }

// ---------- transpose-convert R (1024 x 4096 f32) -> RbT (4096 x 1024 bf16) ----------
__global__ __launch_bounds__(256)
void transposeR(const float* __restrict__ R, unsigned short* __restrict__ Bt) {
  __shared__ float t[64][65];
  const int tx = threadIdx.x & 63, ty = threadIdx.x >> 6;
  const int j0 = blockIdx.x * 64, k0 = blockIdx.y * 64;
#pragma unroll
  for (int i = 0; i < 64; i += 4)
    t[ty + i][tx] = R[(size_t)(k0 + ty + i) * 4096 + j0 + tx];
  __syncthreads();
#pragma unroll
  for (int i = 0; i < 64; i += 4) {
    const int j = ty + i;
    Bt[(size_t)(j0 + j) * 1024 + k0 + tx] = f2bf(t[tx][j]);
  }
}

// ---------- convert h_tm1 -> bf16 ----------
__global__ __launch_bounds__(256)
void convertH(const float* __restrict__ states, unsigned short* __restrict__ hb) {
  const int idx = blockIdx.x * 256 + threadIdx.x;
  const int b = idx >> 8, u = (idx & 255) * 4;
  const float* sp = states + (size_t)b * 1026 + u;
  f32x2 v0 = *(const f32x2*)sp, v1 = *(const f32x2*)(sp + 2);
  u16x4 w;
  w[0] = f2bf(v0[0]); w[1] = f2bf(v0[1]); w[2] = f2bf(v1[0]); w[3] = f2bf(v1[1]);
  *(u16x4*)&hb[(size_t)b * 1024 + u] = w;
}

// ---------- Wg (1024x60 f32) -> WgT (64x1024 bf16, rows 60..63 zero) ----------
__global__ __launch_bounds__(256)
void prep_wgt(const float* __restrict__ Wg, unsigned short* __restrict__ WgT) {
  const int idx = blockIdx.x * 256 + threadIdx.x;
  const int c = idx & 63, kq = idx >> 6;
#pragma unroll
  for (int j = 0; j < 4; ++j) {
    const int k = kq * 4 + j;
    WgT[(size_t)c * 1024 + k] = (c < 60) ? f2bf(Wg[(size_t)k * 60 + c]) : (unsigned short)0;
  }
}

// ================= single-wave GEMM1: 64m x (64z + 64r), fused gates =================
// 1 wave/block, ring-4 LDS (12KB/stage), depth-3 vmcnt, NO barriers in K-loop.
// LDS slot swizzle: 16B-slot s of row r holds k-slot s^((r>>1)&3) (2-way banks max).
__global__ __launch_bounds__(64)
void gemm1w(const unsigned short* __restrict__ A,
            const unsigned short* __restrict__ Bt,
            const int* __restrict__ chv,
            const float* __restrict__ states,
            const float* __restrict__ kcm,
            const float* __restrict__ kd,
            const float* __restrict__ bias_z,
            const float* __restrict__ bias,
            float* __restrict__ zbuf,
            unsigned short* __restrict__ rh) {
  __shared__ __align__(16) char lds[4][12288];
  __shared__ int chs[64];
  __shared__ float d0s[64], d1s[64];

  const int l = threadIdx.x, bid = blockIdx.x;
  const int mt = (bid & 7) * 8 + ((bid >> 3) & 7);   // XCD mt-slab
  const int nt = bid >> 6;
  const int m0 = mt * 64, n0 = nt * 64;

  chs[l] = chv[m0 + l];
  d0s[l] = states[(size_t)(m0 + l) * 1026 + 1024];
  d1s[l] = states[(size_t)(m0 + l) * 1026 + 1025];

  // staging: chunk j (1KB) covers rows [j*16, j*16+16); lane l -> row j*16+(l>>2),
  // k-slot pre-swizzled: (l&3) ^ ((l>>3)&3)  (== (row>>1)&3 within chunk)
  const int srow = l >> 2;
  const int scol = ((l & 3) ^ ((l >> 3) & 3)) * 8;
  const unsigned short* As  = A  + (size_t)(m0 + srow) * 1024 + scol;
  const unsigned short* Bzs = Bt + (size_t)(n0 + srow) * 1024 + scol;
  const unsigned short* Brs = Bt + (size_t)(1024 + n0 + srow) * 1024 + scol;

#define ST1W(rg, k0) { _Pragma("unroll")                                          \
    for (int j = 0; j < 4; ++j) {                                                 \
      gld_lds16(As  + (size_t)j * 16384 + (k0), &lds[rg][j * 1024 + l * 16]);     \
      gld_lds16(Bzs + (size_t)j * 16384 + (k0), &lds[rg][4096 + j * 1024 + l * 16]); \
      gld_lds16(Brs + (size_t)j * 16384 + (k0), &lds[rg][8192 + j * 1024 + l * 16]); } }

  const int arow = l & 15, q = l >> 4;
  const int rdo = (q ^ ((arow >> 1) & 3)) * 16;      // swizzled read slot
  f32x4 accz[4][4] = {}, accr[4][4] = {};

  ST1W(0, 0) ST1W(1, 32) ST1W(2, 64)

#pragma unroll
  for (int t = 0; t < 32; ++t) {
    if (t < 29) ST1W((t + 3) & 3, (t + 3) * 32)
    VMW(t < 29 ? 36 : (t == 29 ? 24 : (t == 30 ? 12 : 0)))
    const char* Lb = lds[t & 3];
    bf16x8 af[4];
#pragma unroll
    for (int mi = 0; mi < 4; ++mi)
      af[mi] = *(const bf16x8*)(Lb + (mi * 16 + arow) * 64 + rdo);
#pragma unroll
    for (int ni = 0; ni < 4; ++ni) {
      const bf16x8 bz = *(const bf16x8*)(Lb + 4096 + (ni * 16 + arow) * 64 + rdo);
#pragma unroll
      for (int mi = 0; mi < 4; ++mi) accz[mi][ni] = MFMA(af[mi], bz, accz[mi][ni]);
      const bf16x8 br = *(const bf16x8*)(Lb + 8192 + (ni * 16 + arow) * 64 + rdo);
#pragma unroll
      for (int mi = 0; mi < 4; ++mi) accr[mi][ni] = MFMA(af[mi], br, accr[mi][ni]);
    }
  }
#undef ST1W

#pragma unroll
  for (int mi = 0; mi < 4; ++mi) {
#pragma unroll
    for (int i = 0; i < 4; ++i) {
      const int lrow = mi * 16 + q * 4 + i;
      const int grow = m0 + lrow;
      const int ch = chs[lrow];
      const float d0 = d0s[lrow], d1 = d1s[lrow];
      const float* kcr = kcm + (size_t)ch * 4096;
#pragma unroll
      for (int ni = 0; ni < 4; ++ni) {
        const int jc = n0 + ni * 16 + arow;
        const float vz = accz[mi][ni][i] + kcr[jc]
                       + d0 * kd[jc] + d1 * kd[4096 + jc] + bias_z[jc];
        const float vr = accr[mi][ni][i] + kcr[1024 + jc]
                       + d0 * kd[1024 + jc] + d1 * kd[4096 + 1024 + jc] + bias[jc];
        const float z = sigmoidf(vz);
        const float rr = sigmoidf(vr);
        zbuf[(size_t)grow * 1024 + jc] = z;
        rh[(size_t)grow * 1024 + jc] = f2bf(rr * bf2f(A[(size_t)grow * 1024 + jc]));
      }
    }
  }
}

// ================= single-wave GEMM 2/3: 64x64 =================
template<int EPI>
__global__ __launch_bounds__(64)
void gemmw(const unsigned short* __restrict__ A,
           const unsigned short* __restrict__ Bt,   // pre-offset panel base
           const int* __restrict__ chv,
           const float* __restrict__ states,
           const float* __restrict__ kcm, int colbase,
           const float* __restrict__ kd,
           const float* __restrict__ bias, int biasoff,
           const float* __restrict__ zbuf,
           float* __restrict__ outp,
           unsigned short* __restrict__ hb2) {
  __shared__ __align__(16) char lds[4][8192];
  __shared__ int chs[64];
  __shared__ float d0s[64], d1s[64];

  const int l = threadIdx.x, bid = blockIdx.x;
  const int mt = (bid & 7) * 8 + ((bid >> 3) & 7);
  const int nt = bid >> 6;
  const int m0 = mt * 64, n0 = nt * 64;

  chs[l] = chv[m0 + l];
  d0s[l] = states[(size_t)(m0 + l) * 1026 + 1024];
  d1s[l] = states[(size_t)(m0 + l) * 1026 + 1025];

  const int srow = l >> 2;
  const int scol = ((l & 3) ^ ((l >> 3) & 3)) * 8;
  const unsigned short* As = A  + (size_t)(m0 + srow) * 1024 + scol;
  const unsigned short* Bs = Bt + (size_t)(n0 + srow) * 1024 + scol;

#define STW(rg, k0) { _Pragma("unroll")                                           \
    for (int j = 0; j < 4; ++j) {                                                 \
      gld_lds16(As + (size_t)j * 16384 + (k0), &lds[rg][j * 1024 + l * 16]);      \
      gld_lds16(Bs + (size_t)j * 16384 + (k0), &lds[rg][4096 + j * 1024 + l * 16]); } }

  const int arow = l & 15, q = l >> 4;
  const int rdo = (q ^ ((arow >> 1) & 3)) * 16;
  f32x4 acc[4][4] = {};

  STW(0, 0) STW(1, 32) STW(2, 64)

#pragma unroll
  for (int t = 0; t < 32; ++t) {
    if (t < 29) STW((t + 3) & 3, (t + 3) * 32)
    VMW(t < 29 ? 24 : (t == 29 ? 16 : (t == 30 ? 8 : 0)))
    const char* Lb = lds[t & 3];
    bf16x8 af[4];
#pragma unroll
    for (int mi = 0; mi < 4; ++mi)
      af[mi] = *(const bf16x8*)(Lb + (mi * 16 + arow) * 64 + rdo);
#pragma unroll
    for (int ni = 0; ni < 4; ++ni) {
      const bf16x8 bf_ = *(const bf16x8*)(Lb + 4096 + (ni * 16 + arow) * 64 + rdo);
#pragma unroll
      for (int mi = 0; mi < 4; ++mi) acc[mi][ni] = MFMA(af[mi], bf_, acc[mi][ni]);
    }
  }
#undef STW

#pragma unroll
  for (int mi = 0; mi < 4; ++mi) {
#pragma unroll
    for (int i = 0; i < 4; ++i) {
      const int lrow = mi * 16 + q * 4 + i;
      const int grow = m0 + lrow;
      const int ch = chs[lrow];
      const float d0 = d0s[lrow], d1 = d1s[lrow];
      const float* kcr = kcm + (size_t)ch * 4096 + colbase;
#pragma unroll
      for (int ni = 0; ni < 4; ++ni) {
        const int gc = n0 + ni * 16 + arow;
        const float v = acc[mi][ni][i] + kcr[gc]
                      + d0 * kd[colbase + gc] + d1 * kd[4096 + colbase + gc]
                      + bias[biasoff + gc];
        if (EPI == 2) {
          const float hh = tanhf(v);
          const float z = zbuf[(size_t)grow * 1024 + gc];
          const float htm = states[(size_t)grow * 1026 + gc];
          const float h = z * htm + (1.f - z) * hh;
          outp[(size_t)grow * NS_STRIDE + gc] = h;
          hb2[(size_t)grow * 1024 + gc] = f2bf(h);
        } else {
          const float o = tanhf(v);
          outp[(size_t)grow * OUT_STRIDE + gc] = o;
          hb2[(size_t)grow * 1024 + gc] = f2bf(o);
        }
      }
    }
  }
}

// ---------- MFMA GMM head (unchanged from R10) ----------
__global__ __launch_bounds__(256)
void gmm2(const unsigned short* __restrict__ ob,
          const unsigned short* __restrict__ WgT,
          const float* __restrict__ bg,
          float* __restrict__ outp,
          float* __restrict__ ns) {
  __shared__ float red[3 * 16 * 64];
  const int tid = threadIdx.x, lane = tid & 63, wave = tid >> 6;
  const int arow = lane & 15, q = lane >> 4;
  const int r0 = blockIdx.x * 16;

  const unsigned short* Al = ob  + (size_t)(r0 + arow) * 1024 + q * 8 + wave * 256;
  const unsigned short* Bl = WgT + (size_t)arow * 1024 + q * 8 + wave * 256;

  f32x4 acc[4] = {};
#pragma unroll
  for (int t = 0; t < 8; ++t) {
    const bf16x8 af = *(const bf16x8*)(Al + t * 32);
#pragma unroll
    for (int ni = 0; ni < 4; ++ni) {
      const bf16x8 bf_ = *(const bf16x8*)(Bl + (size_t)ni * 16 * 1024 + t * 32);
      acc[ni] = MFMA(af, bf_, acc[ni]);
    }
  }

  if (wave) {
#pragma unroll
    for (int ni = 0; ni < 4; ++ni)
#pragma unroll
      for (int i = 0; i < 4; ++i)
        red[(wave - 1) * 1024 + (ni * 4 + i) * 64 + lane] = acc[ni][i];
  }
  __syncthreads();
  if (wave == 0) {
#pragma unroll
    for (int w = 0; w < 3; ++w)
#pragma unroll
      for (int ni = 0; ni < 4; ++ni)
#pragma unroll
        for (int i = 0; i < 4; ++i)
          acc[ni][i] += red[w * 1024 + (ni * 4 + i) * 64 + lane];

    const int gb = lane & 48;
#pragma unroll
    for (int i = 0; i < 4; ++i) {
      float g0 = acc[0][i] + bg[arow];
      float g1 = acc[1][i] + ((16 + arow < 60) ? bg[16 + arow] : 0.f);
      float g2 = acc[2][i] + ((32 + arow < 60) ? bg[32 + arow] : 0.f);
      float g3 = acc[3][i] + ((48 + arow < 60) ? bg[48 + arow] : 0.f);

      const float e0 = fminf(fmaxf(expf(g0), 1e-10f), 1e10f);
      const float e1 = (arow < 4) ? fminf(fmaxf(expf(g1), 1e-10f), 1e10f) : 0.f;
      float s = e0 + e1;
#pragma unroll
      for (int m = 1; m < 16; m <<= 1) s += __shfl_xor(s, m, 64);
      const float pi0 = e0 / s;
      const float pi1 = e1 / s;

      const float t1 = __shfl(g1, gb | ((arow + 4) & 15), 64);
      const float t2 = __shfl(g2, gb | ((arow + 4) & 15), 64);
      const float muxA = (arow < 12) ? t1 : t2;
      const float muxB = t2;
      const float u1 = __shfl(g2, gb | ((arow + 8) & 15), 64);
      const float u2 = __shfl(g3, gb | ((arow + 8) & 15), 64);
      const float muyA = (arow < 8) ? u1 : u2;
      const float muyB = u2;

      float px = pi0 * muxA + ((arow < 4) ? pi1 * muxB : 0.f);
      float py = pi0 * muyA + ((arow < 4) ? pi1 * muyB : 0.f);
#pragma unroll
      for (int m = 1; m < 16; m <<= 1) {
        px += __shfl_xor(px, m, 64);
        py += __shfl_xor(py, m, 64);
      }

      const int row = r0 + q * 4 + i;
      float* orow = outp + (size_t)row * OUT_STRIDE;
      orow[1024 + arow] = pi0;
      if (arow < 4)  orow[1040 + arow] = pi1;
      if (arow >= 4) orow[1040 + arow] = g1;
      orow[1056 + arow] = g2;
      if (arow < 12) orow[1072 + arow] = g3;
      if (arow == 0) {
        orow[1084] = px;
        orow[1085] = py;
        ns[(size_t)row * NS_STRIDE + 1024] = px;
        ns[(size_t)row * NS_STRIDE + 1025] = py;
      }
    }
  }
}

extern "C" void kernel_launch(void* const* d_in, const int* in_sizes, int n_in,
                              void* d_out, int out_size, void* d_ws, size_t ws_size,
                              hipStream_t stream) {
  const int*   chv    = (const int*)d_in[0];
  const float* states = (const float*)d_in[1];
  const float* bias_z = (const float*)d_in[2];
  const float* R      = (const float*)d_in[3];
  const float* kc     = (const float*)d_in[4];
  const float* bias   = (const float*)d_in[5];
  const float* kd     = (const float*)d_in[6];
  const float* Wg     = (const float*)d_in[7];
  const float* bg     = (const float*)d_in[8];
  float* out = (float*)d_out;

  char* ws = (char*)d_ws;
  unsigned short* RbT  = (unsigned short*)ws;                   // 8 MB
  unsigned short* hb   = (unsigned short*)(ws + 8388608);       // 8 MB (reused as bf16 o)
  unsigned short* rh   = (unsigned short*)(ws + 16777216);      // 8 MB
  unsigned short* hb2  = (unsigned short*)(ws + 25165824);      // 8 MB
  float*          zbuf = (float*)(ws + 33554432);               // 16 MB
  unsigned short* WgT  = (unsigned short*)(ws + 50331648);      // 128 KB

  transposeR<<<dim3(64, 16), 256, 0, stream>>>(R, RbT);
  convertH<<<4096, 256, 0, stream>>>(states, hb);
  prep_wgt<<<64, 256, 0, stream>>>(Wg, WgT);

  // GEMM1: z + r gates (single-wave blocks, 64m x (64z+64r))
  gemm1w<<<1024, 64, 0, stream>>>(hb, RbT, chv, states, kc, kd, bias_z, bias, zbuf, rh);

  // GEMM2: hh -> h
  gemmw<2><<<1024, 64, 0, stream>>>(rh, RbT + (size_t)2048 * 1024,
      chv, states, kc, 2048, kd, bias, 1024, zbuf, out + NS_BASE, hb2);

  // GEMM3: o (f32 to out, bf16 to hb for the head)
  gemmw<3><<<1024, 64, 0, stream>>>(hb2, RbT + (size_t)3072 * 1024,
      chv, states, kc, 3072, kd, bias, 2048, nullptr, out, hb);

  gmm2<<<256, 256, 0, stream>>>(hb, WgT, bg, out, out + NS_BASE);
}